// Round 11
// baseline (106.648 us; speedup 1.0000x reference)
//
#include <hip/hip_runtime.h>
#include <hip/hip_bf16.h>

#define MDIM 8192
#define KDIM 256
#define NB 64        // 8192/128 tiles per dim
#define NTILES 2080  // NB*(NB+1)/2 upper-triangle tiles
#define NBLK 512     // persistent blocks, 2 per CU

typedef __attribute__((ext_vector_type(8))) short short8;
typedef __attribute__((ext_vector_type(4))) float f32x4;

__device__ __forceinline__ ushort bf16u(float f) {
    __hip_bfloat16 h = __float2bfloat16(f);
    return *reinterpret_cast<ushort*>(&h);
}

// async global->LDS, 16B per lane; LDS dest = wave-uniform base + lane*16.
__device__ __forceinline__ void async16(ushort* lds, const ushort* g) {
    __builtin_amdgcn_global_load_lds(
        (const __attribute__((address_space(1))) void*)g,
        (__attribute__((address_space(3))) void*)lds, 16, 0, 0);
}

// Kernel 1: each wave owns the row pair (i, i+4096): normalizes both rows to bf16,
// computes pos[i] = pos[i+4096] = 10*cos(x_i, x_p) in fp32, zeros row_sum.
__global__ __launch_bounds__(256) void knorm(const float* __restrict__ x,
                                             ushort* __restrict__ xn,
                                             float* __restrict__ row_sum,
                                             float* __restrict__ pos) {
    const int wave = threadIdx.x >> 6, lane = threadIdx.x & 63;
    const int i = blockIdx.x * 4 + wave;  // 0..4095
    const int p = i + 4096;
    const float4 a = *reinterpret_cast<const float4*>(x + (size_t)i * KDIM + lane * 4);
    const float4 b = *reinterpret_cast<const float4*>(x + (size_t)p * KDIM + lane * 4);
    float sa = a.x * a.x + a.y * a.y + a.z * a.z + a.w * a.w;
    float sb = b.x * b.x + b.y * b.y + b.z * b.z + b.w * b.w;
    float sab = a.x * b.x + a.y * b.y + a.z * b.z + a.w * b.w;
#pragma unroll
    for (int m = 1; m < 64; m <<= 1) {
        sa += __shfl_xor(sa, m, 64);
        sb += __shfl_xor(sb, m, 64);
        sab += __shfl_xor(sab, m, 64);
    }
    const float ia = 1.0f / fmaxf(sqrtf(sa), 1e-8f);
    const float ib = 1.0f / fmaxf(sqrtf(sb), 1e-8f);
    ushort4 oa, ob;
    oa.x = bf16u(a.x * ia); oa.y = bf16u(a.y * ia);
    oa.z = bf16u(a.z * ia); oa.w = bf16u(a.w * ia);
    ob.x = bf16u(b.x * ib); ob.y = bf16u(b.y * ib);
    ob.z = bf16u(b.z * ib); ob.w = bf16u(b.w * ib);
    *reinterpret_cast<ushort4*>(xn + (size_t)i * KDIM + lane * 4) = oa;
    *reinterpret_cast<ushort4*>(xn + (size_t)p * KDIM + lane * 4) = ob;
    if (lane == 0) {
        const float pv = 10.0f * sab * ia * ib;
        pos[i] = pv;
        pos[p] = pv;
    }
    if (threadIdx.x < 8) row_sum[blockIdx.x * 8 + threadIdx.x] = 0.0f;
}

// Kernel 2: EXACT R4 structure (best measured: ksim ~42 us), templated for
// within-probe ablation (m164/m177 method):
//   V0 = full (real output)          V1 = stage+vmcnt+barriers only
//   V2 = V1 + ds_read/MFMA (acc kept live via asm, rule 17)
//   V3 = ds_read/MFMA + epilogue, NO staging (stale LDS; barriers kept)
// Reads: V1 = skeleton cost; V2-V1 = compute add-on; V0-V2 = epilogue;
// V0-V3 = staging exposure.
template <int V>
__global__ __launch_bounds__(256) void ksim(const ushort* __restrict__ xn,
                                            float* __restrict__ row_sum) {
    __shared__ ushort As[2][8192];
    __shared__ ushort Bs[2][8192];

    const int blk = blockIdx.x;
    const int t0 = (blk * NTILES) >> 9;
    const int t1 = ((blk + 1) * NTILES) >> 9;
    const int S = 4 * (t1 - t0);  // flat chunk-steps (BK=64)

    // decode t0 -> (bi, bj), row-major upper triangle
    int bi = (int)((129.0f - sqrtf(16641.0f - 8.0f * (float)t0)) * 0.5f);
    while (NB * bi - bi * (bi - 1) / 2 > t0) --bi;
    while (NB * (bi + 1) - (bi + 1) * bi / 2 <= t0) ++bi;
    int bj = bi + (t0 - (NB * bi - bi * (bi - 1) / 2));

    const int t = threadIdx.x;
    const int wave = t >> 6, lane = t & 63;
    const int l16 = lane & 15, lhi = lane >> 4;
    const int wRow = (wave >> 1) * 64, wCol = (wave & 1) * 64;
    const bool wdiag = (wRow == wCol);
    const int srcc = 8 * ((lane & 7) ^ (lane >> 3));
    const int subrow = lane >> 3;
    const int sw = (l16 & 7) << 3;

    int sbi = bi, sbj = bj, sc = 0, sstep = 0;
    auto stage1 = [&]() {
        const size_t rbase = (size_t)sbi * 128 * KDIM;
        const size_t cbase = (size_t)sbj * 128 * KDIM;
        const int kk = sc * 64;
        const int buf = sstep & 1;
#pragma unroll
        for (int q = 0; q < 4; ++q) {
            const int rr = (wave * 4 + q) * 8 + subrow;
            async16(&As[buf][(wave * 4 + q) * 512], xn + rbase + (size_t)rr * KDIM + kk + srcc);
        }
#pragma unroll
        for (int q = 0; q < 4; ++q) {
            const int rr = (wave * 4 + q) * 8 + subrow;
            async16(&Bs[buf][(wave * 4 + q) * 512], xn + cbase + (size_t)rr * KDIM + kk + srcc);
        }
        ++sstep;
        if (++sc == 4) {
            sc = 0;
            if (++sbj == NB) { ++sbi; sbj = sbi; }
        }
    };

    f32x4 acc[4][4];
    float prsum[4][4];
#pragma unroll
    for (int a = 0; a < 4; ++a)
#pragma unroll
        for (int b = 0; b < 4; ++b) {
            acc[a][b] = (f32x4){0.f, 0.f, 0.f, 0.f};
            prsum[a][b] = 0.f;
        }

    auto compute = [&](int buf) {
        __builtin_amdgcn_s_setprio(1);
#pragma unroll
        for (int k2 = 0; k2 < 2; ++k2) {
            const int ko = k2 * 32 + lhi * 8;
            short8 a[4], bb[4];
#pragma unroll
            for (int f = 0; f < 4; ++f)
                a[f] = *reinterpret_cast<const short8*>(
                    &As[buf][(wRow + f * 16 + l16) * 64 + (ko ^ sw)]);
#pragma unroll
            for (int f = 0; f < 4; ++f)
                bb[f] = *reinterpret_cast<const short8*>(
                    &Bs[buf][(wCol + f * 16 + l16) * 64 + (ko ^ sw)]);
#pragma unroll
            for (int fr = 0; fr < 4; ++fr)
#pragma unroll
                for (int fc = 0; fc < 4; ++fc)
                    acc[fr][fc] = __builtin_amdgcn_mfma_f32_16x16x32_bf16(
                        a[fr], bb[fc], acc[fr][fc], 0, 0, 0);
        }
        __builtin_amdgcn_s_setprio(0);
    };

    stage1();  // step 0
    stage1();  // step 1
    int cstep = 0;

    for (int tt = t0; tt < t1; ++tt) {
#pragma unroll
        for (int c = 0; c < 4; ++c, ++cstep) {
            if constexpr (V == 3) {
                asm volatile("s_barrier" ::: "memory");
            } else {
                if (cstep == S - 1)
                    asm volatile("s_waitcnt vmcnt(0)\n\ts_barrier" ::: "memory");
                else
                    asm volatile("s_waitcnt vmcnt(8)\n\ts_barrier" ::: "memory");
            }
            if constexpr (V != 1) compute(cstep & 1);
            asm volatile("s_barrier" ::: "memory");
            if constexpr (V != 3) {
                if (sstep < S) stage1();
            }
        }

        if constexpr (V == 0 || V == 3) {
            // ---- tile epilogue ----
            const bool diag = (bi == bj);
            if (diag) {
#pragma unroll
                for (int fr = 0; fr < 4; ++fr)
#pragma unroll
                    for (int fc = 0; fc < 4; ++fc)
#pragma unroll
                        for (int j = 0; j < 4; ++j) {
                            float e = __expf(acc[fr][fc][j] * 10.0f);
                            if (wdiag && fr == fc && l16 == lhi * 4 + j) e = 0.0f;
                            prsum[fr][j] += e;
                            acc[fr][fc][j] = 0.0f;
                        }
            } else {
                float csum[4] = {0.f, 0.f, 0.f, 0.f};
#pragma unroll
                for (int fr = 0; fr < 4; ++fr)
#pragma unroll
                    for (int fc = 0; fc < 4; ++fc)
#pragma unroll
                        for (int j = 0; j < 4; ++j) {
                            const float e = __expf(acc[fr][fc][j] * 10.0f);
                            prsum[fr][j] += e;
                            csum[fc] += e;
                            acc[fr][fc][j] = 0.0f;
                        }
#pragma unroll
                for (int fc = 0; fc < 4; ++fc) {
                    float s = csum[fc];
                    s += __shfl_xor(s, 16, 64);
                    s += __shfl_xor(s, 32, 64);
                    if (lhi == 0)
                        atomicAdd(&row_sum[bj * 128 + wCol + fc * 16 + l16], s);
                }
            }
            int nbi = bi, nbj = bj + 1;
            if (nbj == NB) { nbi = bi + 1; nbj = nbi; }
            if (tt == t1 - 1 || nbi != bi) {
#pragma unroll
                for (int fr = 0; fr < 4; ++fr)
#pragma unroll
                    for (int j = 0; j < 4; ++j) {
                        float s = prsum[fr][j];
                        s += __shfl_xor(s, 1, 16);
                        s += __shfl_xor(s, 2, 16);
                        s += __shfl_xor(s, 4, 16);
                        s += __shfl_xor(s, 8, 16);
                        if (l16 == 0)
                            atomicAdd(&row_sum[bi * 128 + wRow + fr * 16 + lhi * 4 + j], s);
                        prsum[fr][j] = 0.f;
                    }
            }
            bi = nbi;
            bj = nbj;
        }
    }

    if constexpr (V == 2) {
        // keep all MFMA results live without epilogue cost (rule 17: anti-DCE)
#pragma unroll
        for (int a = 0; a < 4; ++a)
#pragma unroll
            for (int b = 0; b < 4; ++b)
                asm volatile("" ::"v"(acc[a][b][0]), "v"(acc[a][b][1]),
                             "v"(acc[a][b][2]), "v"(acc[a][b][3]));
    }
}

// Kernel 3: loss = mean_i( log(row_sum[i]) - pos[i] )
__global__ __launch_bounds__(1024) void kfinal(const float* __restrict__ row_sum,
                                               const float* __restrict__ pos,
                                               float* __restrict__ out) {
    float acc = 0.f;
    for (int i = threadIdx.x; i < MDIM; i += 1024)
        acc += logf(row_sum[i]) - pos[i];
#pragma unroll
    for (int m = 1; m < 64; m <<= 1) acc += __shfl_xor(acc, m, 64);
    __shared__ float w[16];
    if ((threadIdx.x & 63) == 0) w[threadIdx.x >> 6] = acc;
    __syncthreads();
    if (threadIdx.x == 0) {
        float s = 0.f;
#pragma unroll
        for (int i = 0; i < 16; ++i) s += w[i];
        out[0] = s / (float)MDIM;
    }
}

extern "C" void kernel_launch(void* const* d_in, const int* in_sizes, int n_in,
                              void* d_out, int out_size, void* d_ws, size_t ws_size,
                              hipStream_t stream) {
    const float* x = (const float*)d_in[0];
    float* out = (float*)d_out;

    char* ws = (char*)d_ws;
    ushort* xn = (ushort*)ws;                                  // 8192*256*2 = 4 MB
    float* row_sum = (float*)(ws + (size_t)MDIM * KDIM * 2);   // 32 KB
    float* pos = row_sum + MDIM;                               // 32 KB
    float* dummy = pos + MDIM;                                 // ablation sink

    knorm<<<MDIM / 8, 256, 0, stream>>>(x, xn, row_sum, pos);

    // Ablation dispatches (sinks); real compute is the V0 dispatch.
    ksim<1><<<NBLK, 256, 0, stream>>>(xn, dummy);
    ksim<2><<<NBLK, 256, 0, stream>>>(xn, dummy);
    ksim<3><<<NBLK, 256, 0, stream>>>(xn, dummy);
    ksim<0><<<NBLK, 256, 0, stream>>>(xn, row_sum);

    kfinal<<<1, 1024, 0, stream>>>(row_sum, pos, out);
}

// Round 12
// 82.497 us; speedup vs baseline: 1.2927x; 1.2927x over previous
//
#include <hip/hip_runtime.h>
#include <hip/hip_bf16.h>

#define MDIM 8192
#define KDIM 256
#define NB 64        // 8192/128 tiles per dim
#define NTILES 2080  // NB*(NB+1)/2 upper-triangle tiles

typedef __attribute__((ext_vector_type(8))) short short8;
typedef __attribute__((ext_vector_type(4))) float f32x4;

__device__ __forceinline__ ushort bf16u(float f) {
    __hip_bfloat16 h = __float2bfloat16(f);
    return *reinterpret_cast<ushort*>(&h);
}

// Kernel 1: each wave owns the row pair (i, i+4096): normalizes both rows to bf16,
// computes pos[i] = pos[i+4096] = 10*cos(x_i, x_p) in fp32, zeros row_sum.
__global__ __launch_bounds__(256) void knorm(const float* __restrict__ x,
                                             ushort* __restrict__ xn,
                                             float* __restrict__ row_sum,
                                             float* __restrict__ pos) {
    const int wave = threadIdx.x >> 6, lane = threadIdx.x & 63;
    const int i = blockIdx.x * 4 + wave;  // 0..4095
    const int p = i + 4096;
    const float4 a = *reinterpret_cast<const float4*>(x + (size_t)i * KDIM + lane * 4);
    const float4 b = *reinterpret_cast<const float4*>(x + (size_t)p * KDIM + lane * 4);
    float sa = a.x * a.x + a.y * a.y + a.z * a.z + a.w * a.w;
    float sb = b.x * b.x + b.y * b.y + b.z * b.z + b.w * b.w;
    float sab = a.x * b.x + a.y * b.y + a.z * b.z + a.w * b.w;
#pragma unroll
    for (int m = 1; m < 64; m <<= 1) {
        sa += __shfl_xor(sa, m, 64);
        sb += __shfl_xor(sb, m, 64);
        sab += __shfl_xor(sab, m, 64);
    }
    const float ia = 1.0f / fmaxf(sqrtf(sa), 1e-8f);
    const float ib = 1.0f / fmaxf(sqrtf(sb), 1e-8f);
    ushort4 oa, ob;
    oa.x = bf16u(a.x * ia); oa.y = bf16u(a.y * ia);
    oa.z = bf16u(a.z * ia); oa.w = bf16u(a.w * ia);
    ob.x = bf16u(b.x * ib); ob.y = bf16u(b.y * ib);
    ob.z = bf16u(b.z * ib); ob.w = bf16u(b.w * ib);
    *reinterpret_cast<ushort4*>(xn + (size_t)i * KDIM + lane * 4) = oa;
    *reinterpret_cast<ushort4*>(xn + (size_t)p * KDIM + lane * 4) = ob;
    if (lane == 0) {
        const float pv = 10.0f * sab * ia * ib;
        pos[i] = pv;
        pos[p] = pv;
    }
    if (threadIdx.x < 8) row_sum[blockIdx.x * 8 + threadIdx.x] = 0.0f;
}

// Kernel 2: direct-from-L2 GEMM. R11 ablation: the stage+vmcnt+barrier skeleton
// alone is ~half the R4 kernel, so remove it entirely. No LDS, no barriers, no
// waitcnt: each wave loads its MFMA fragments straight from xn (4 MiB = exactly
// one XCD L2; chunked XCD swizzle keeps each XCD's tile range L2-local) in a
// fully-unrolled K-loop the compiler software-pipelines. One 128x128 tile per
// block (grid 2080 -> zero tail imbalance), 4 waves (2x2), acc[4][4]/wave.
// A-fragment rows are shared by 2 waves, B-cols by 2 waves -> sibling reads hit
// L1. Epilogue: exp + symmetric row/col fold, batched 16-lane atomics.
__global__ __launch_bounds__(256, 3) void ksim(const ushort* __restrict__ xn,
                                               float* __restrict__ row_sum) {
    const int bid = blockIdx.x;
    const int blk = (bid & 7) * 260 + (bid >> 3);  // XCD chunk swizzle (2080 = 8*260)

    // decode blk -> (bi, bj), row-major upper triangle
    int bi = (int)((129.0f - sqrtf(16641.0f - 8.0f * (float)blk)) * 0.5f);
    while (NB * bi - bi * (bi - 1) / 2 > blk) --bi;
    while (NB * (bi + 1) - (bi + 1) * bi / 2 <= blk) ++bi;
    const int bj = bi + (blk - (NB * bi - bi * (bi - 1) / 2));
    const bool diag = (bi == bj);

    const int t = threadIdx.x;
    const int wave = t >> 6, lane = t & 63;
    const int l16 = lane & 15, lhi = lane >> 4;
    const int wRow = (wave >> 1) * 64, wCol = (wave & 1) * 64;

    // fragment bases: lane reads row (base + m*16 + l16), k-slab (k2*32 + lhi*8)
    const ushort* Abase = xn + (size_t)(bi * 128 + wRow + l16) * KDIM + lhi * 8;
    const ushort* Bbase = xn + (size_t)(bj * 128 + wCol + l16) * KDIM + lhi * 8;

    f32x4 acc[4][4];
#pragma unroll
    for (int m = 0; m < 4; ++m)
#pragma unroll
        for (int n = 0; n < 4; ++n) acc[m][n] = (f32x4){0.f, 0.f, 0.f, 0.f};

    // ---- K-loop: straight-line loads + MFMA; compiler pipelines across k2 ----
#pragma unroll
    for (int k2 = 0; k2 < 8; ++k2) {
        short8 a[4], b[4];
#pragma unroll
        for (int m = 0; m < 4; ++m)
            a[m] = *reinterpret_cast<const short8*>(Abase + (size_t)m * 16 * KDIM + k2 * 32);
#pragma unroll
        for (int n = 0; n < 4; ++n)
            b[n] = *reinterpret_cast<const short8*>(Bbase + (size_t)n * 16 * KDIM + k2 * 32);
#pragma unroll
        for (int m = 0; m < 4; ++m)
#pragma unroll
            for (int n = 0; n < 4; ++n)
                acc[m][n] = __builtin_amdgcn_mfma_f32_16x16x32_bf16(
                    a[m], b[n], acc[m][n], 0, 0, 0);
    }

    // ---- epilogue: e = exp(10*sim); rows via psum, cols via csum (symmetry) ----
    float csum[4] = {0.f, 0.f, 0.f, 0.f};
#pragma unroll
    for (int m = 0; m < 4; ++m) {
        float psum[4] = {0.f, 0.f, 0.f, 0.f};
#pragma unroll
        for (int n = 0; n < 4; ++n)
#pragma unroll
            for (int j = 0; j < 4; ++j) {
                float e = __expf(acc[m][n][j] * 10.0f);
                if (diag && (wRow + m * 16 + lhi * 4 + j) == (wCol + n * 16 + l16))
                    e = 0.0f;  // exclude self-similarity
                psum[j] += e;
                csum[n] += e;
            }
        // reduce each psum[j] across the 16 l16-lanes (all lanes end with totals)
#pragma unroll
        for (int j = 0; j < 4; ++j) {
            psum[j] += __shfl_xor(psum[j], 1, 16);
            psum[j] += __shfl_xor(psum[j], 2, 16);
            psum[j] += __shfl_xor(psum[j], 4, 16);
            psum[j] += __shfl_xor(psum[j], 8, 16);
        }
        // batched row atomics: lane (lhi, l16<4) owns row m*16 + lhi*4 + (l16&3);
        // 16 active lanes, 16 consecutive addresses, one instruction per m.
        const float rv = (l16 & 2) ? ((l16 & 1) ? psum[3] : psum[2])
                                   : ((l16 & 1) ? psum[1] : psum[0]);
        if (l16 < 4)
            atomicAdd(&row_sum[bi * 128 + wRow + m * 16 + lhi * 4 + (l16 & 3)], rv);
    }
    if (!diag) {  // fold this tile's exp-sums into its column rows (transpose half)
#pragma unroll
        for (int n = 0; n < 4; ++n) {
            csum[n] += __shfl_xor(csum[n], 16, 64);
            csum[n] += __shfl_xor(csum[n], 32, 64);
        }
        if (lhi == 0) {
#pragma unroll
            for (int n = 0; n < 4; ++n)
                atomicAdd(&row_sum[bj * 128 + wCol + n * 16 + l16], csum[n]);
        }
    }
}

// Kernel 3: loss = mean_i( log(row_sum[i]) - pos[i] )
__global__ __launch_bounds__(1024) void kfinal(const float* __restrict__ row_sum,
                                               const float* __restrict__ pos,
                                               float* __restrict__ out) {
    float acc = 0.f;
    for (int i = threadIdx.x; i < MDIM; i += 1024)
        acc += logf(row_sum[i]) - pos[i];
#pragma unroll
    for (int m = 1; m < 64; m <<= 1) acc += __shfl_xor(acc, m, 64);
    __shared__ float w[16];
    if ((threadIdx.x & 63) == 0) w[threadIdx.x >> 6] = acc;
    __syncthreads();
    if (threadIdx.x == 0) {
        float s = 0.f;
#pragma unroll
        for (int i = 0; i < 16; ++i) s += w[i];
        out[0] = s / (float)MDIM;
    }
}

extern "C" void kernel_launch(void* const* d_in, const int* in_sizes, int n_in,
                              void* d_out, int out_size, void* d_ws, size_t ws_size,
                              hipStream_t stream) {
    const float* x = (const float*)d_in[0];
    float* out = (float*)d_out;

    char* ws = (char*)d_ws;
    ushort* xn = (ushort*)ws;                                  // 8192*256*2 = 4 MB
    float* row_sum = (float*)(ws + (size_t)MDIM * KDIM * 2);   // 32 KB
    float* pos = row_sum + MDIM;                               // 32 KB

    knorm<<<MDIM / 8, 256, 0, stream>>>(x, xn, row_sum, pos);
    ksim<<<NTILES, 256, 0, stream>>>(xn, row_sum);
    kfinal<<<1, 1024, 0, stream>>>(row_sum, pos, out);
}